// Round 3
// baseline (171.442 us; speedup 1.0000x reference)
//
#include <hip/hip_runtime.h>
#include <math.h>

// Problem constants
#define DIM   256
#define NST   256
#define LSEQ  512
#define BAT   2
#define DTSZ  64
#define PCOLS 576
#define NROWS (BAT*LSEQ)   // 1024

// proj split-k config
#define KSPLIT 4
#define KLEN   (DIM/KSPLIT)   // 64
#define AROWS  8              // rows per projA block
#define BROWS  4              // rows per projB block

// scan config
constexpr int C  = 16;         // chunks over L
constexpr int LC = LSEQ / C;   // 32 steps per chunk
constexpr int G  = 4;          // d-values per block
constexpr int TR = 4;          // pass3 reduce window
constexpr float LOG2E = 1.4426950408889634f;

__device__ __forceinline__ float fexp2(float v) {
#if __has_builtin(__builtin_amdgcn_exp2f)
    return __builtin_amdgcn_exp2f(v);
#else
    return exp2f(v);
#endif
}

// ---------------- projA: partial x@W_in over a k-range. grid = 128 rowblocks x 4 ksplits.
__global__ __launch_bounds__(256, 2) void projA_kernel(
    const float* __restrict__ x,      // [NROWS, DIM]
    const float* __restrict__ W_in,   // [DIM, PCOLS]
    float* __restrict__ PP)           // [KSPLIT, NROWS, PCOLS]
{
    __shared__ float xs[AROWS][KLEN];
    const int j = threadIdx.x;
    const int kb = blockIdx.x & 3;
    const int row0 = (blockIdx.x >> 2) * AROWS;
    const int k0 = kb * KLEN;

    #pragma unroll
    for (int it = 0; it < 2; ++it) {
        int e = j + it * 256;
        int r = e >> 6, kk = e & 63;
        xs[r][kk] = x[(row0 + r) * DIM + k0 + kk];
    }
    __syncthreads();

    float a0[AROWS], a1[AROWS], a2[AROWS];
    #pragma unroll
    for (int r = 0; r < AROWS; ++r) { a0[r] = 0.f; a1[r] = 0.f; a2[r] = 0.f; }
    const bool has2 = (j < 64);

    #pragma unroll 2
    for (int k4 = 0; k4 < KLEN / 4; ++k4) {
        float w0[4], w1[4], w2[4];
        #pragma unroll
        for (int u = 0; u < 4; ++u) {
            int k = k0 + k4 * 4 + u;
            w0[u] = W_in[k * PCOLS + j];
            w1[u] = W_in[k * PCOLS + 256 + j];
            w2[u] = has2 ? W_in[k * PCOLS + 512 + j] : 0.f;
        }
        #pragma unroll
        for (int r = 0; r < AROWS; ++r) {
            float4 xv = *(const float4*)&xs[r][k4 * 4];   // broadcast b128
            const float xa[4] = {xv.x, xv.y, xv.z, xv.w};
            #pragma unroll
            for (int u = 0; u < 4; ++u) {
                a0[r] = fmaf(xa[u], w0[u], a0[r]);
                a1[r] = fmaf(xa[u], w1[u], a1[r]);
                a2[r] = fmaf(xa[u], w2[u], a2[r]);
            }
        }
    }
    #pragma unroll
    for (int r = 0; r < AROWS; ++r) {
        size_t base = (size_t)(kb * NROWS + row0 + r) * PCOLS;
        PP[base + j]       = a0[r];
        PP[base + 256 + j] = a1[r];
        if (has2) PP[base + 512 + j] = a2[r];
    }
}

// ---------------- projB: reduce k-partials, split cols, dt = softplus(dt_raw@W_dt+b), dtx
__global__ __launch_bounds__(256, 4) void projB_kernel(
    const float* __restrict__ x,
    const float* __restrict__ PP,     // [KSPLIT, NROWS, PCOLS]
    const float* __restrict__ W_dt,   // [DTSZ, DIM]
    const float* __restrict__ b_dt,   // [DIM]
    float* __restrict__ bet, float* __restrict__ gam,
    float* __restrict__ dtp, float* __restrict__ dtxp)
{
    __shared__ float draw[BROWS][DTSZ];
    const int j = threadIdx.x;
    const int row0 = blockIdx.x * BROWS;
    const bool has2 = (j < 64);

    #pragma unroll
    for (int r = 0; r < BROWS; ++r) {
        float s0 = 0.f, s1 = 0.f, s2 = 0.f;
        #pragma unroll
        for (int kb = 0; kb < KSPLIT; ++kb) {
            size_t base = (size_t)(kb * NROWS + row0 + r) * PCOLS;
            s0 += PP[base + j];
            s1 += PP[base + 256 + j];
            s2 += has2 ? PP[base + 512 + j] : 0.f;
        }
        int row = row0 + r;
        if (has2) {
            draw[r][j] = s0;                       // dt_raw col j
            bet[row * NST + 192 + j] = s1;         // proj col 256+j
            gam[row * NST + 192 + j] = s2;         // proj col 512+j
        } else {
            bet[row * NST + (j - 64)] = s0;        // proj col j in [64,320)
            gam[row * NST + (j - 64)] = s1;        // proj col 256+j in [320,512)
        }
    }
    __syncthreads();

    float accd[BROWS];
    float bd = b_dt[j];
    #pragma unroll
    for (int r = 0; r < BROWS; ++r) accd[r] = bd;
    #pragma unroll 4
    for (int k = 0; k < DTSZ; ++k) {
        float w = W_dt[k * DIM + j];
        #pragma unroll
        for (int r = 0; r < BROWS; ++r) accd[r] = fmaf(draw[r][k], w, accd[r]);
    }
    #pragma unroll
    for (int r = 0; r < BROWS; ++r) {
        int row = row0 + r;
        float v = accd[r];
        float sp = (v > 20.f) ? v : log1pf(__expf(v));
        dtp[row * DIM + j]  = sp;
        dtxp[row * DIM + j] = sp * x[row * DIM + j];
    }
}

// ---------------- pass1: per-chunk affine summary (P, Q). grid = B*(D/G)*C = 2048.
__global__ __launch_bounds__(256, 4) void scan_pass1(
    const float* __restrict__ alpha_log,
    const float* __restrict__ bet,
    const float* __restrict__ dtp, const float* __restrict__ dtxp,
    float* __restrict__ PS, float* __restrict__ Q)
{
    __shared__ float dts[LC][G];
    __shared__ float dxs[LC][G];
    const int n    = threadIdx.x;
    const int c    = blockIdx.x & 15;
    const int dblk = (blockIdx.x >> 4) & 63;
    const int b    = blockIdx.x >> 10;
    const int d0   = dblk * G;
    const int rbase = b * LSEQ + c * LC;

    {   // stage dt/dtx for the chunk (LC*G = 128 floats each)
        int t = (n & 127) >> 2, g = n & 3;
        if (n < 128) dts[t][g] = dtp [(rbase + t) * DIM + d0 + g];
        else         dxs[t][g] = dtxp[(rbase + t) * DIM + d0 + g];
    }
    float aln[G];
    #pragma unroll
    for (int g = 0; g < G; ++g)
        aln[g] = -__expf(alpha_log[(d0 + g) * NST + n]) * LOG2E;
    __syncthreads();

    float p[G], q[G];
    #pragma unroll
    for (int g = 0; g < G; ++g) { p[g] = 1.f; q[g] = 0.f; }

    constexpr int W = 8, NW = LC / W;
    float be[2][W];
    #pragma unroll
    for (int t = 0; t < W; ++t) be[0][t] = bet[(rbase + t) * NST + n];

    #pragma unroll
    for (int w = 0; w < NW; ++w) {
        const int cur = w & 1, nxt = cur ^ 1;
        if (w + 1 < NW) {     // prefetch next window while computing this one
            #pragma unroll
            for (int t = 0; t < W; ++t)
                be[nxt][t] = bet[(rbase + (w + 1) * W + t) * NST + n];
        }
        #pragma unroll
        for (int t = 0; t < W; ++t) {
            float4 dt4 = *(const float4*)&dts[w * W + t][0];
            float4 dx4 = *(const float4*)&dxs[w * W + t][0];
            const float dta[4] = {dt4.x, dt4.y, dt4.z, dt4.w};
            const float dxa[4] = {dx4.x, dx4.y, dx4.z, dx4.w};
            #pragma unroll
            for (int g = 0; g < G; ++g) {
                float a = fexp2(dta[g] * aln[g]);
                q[g] = fmaf(a, q[g], dxa[g] * be[cur][t]);
                p[g] *= a;
            }
        }
    }
    #pragma unroll
    for (int g = 0; g < G; ++g) {
        size_t i = ((size_t)(b * DIM + d0 + g) * C + c) * NST + n;
        PS[i] = p[g]; Q[i] = q[g];
    }
}

// ---------------- pass2: combine chunk summaries -> chunk entry states (in-place in PS)
__global__ __launch_bounds__(256) void scan_pass2(
    float* __restrict__ PS, const float* __restrict__ Q)
{
    const int n = threadIdx.x;
    const size_t base = (size_t)blockIdx.x * C * NST + n;
    float p[C], q[C];
    #pragma unroll
    for (int c = 0; c < C; ++c) { p[c] = PS[base + c * NST]; q[c] = Q[base + c * NST]; }
    float s = 0.f;
    #pragma unroll
    for (int c = 0; c < C; ++c) { PS[base + c * NST] = s; s = fmaf(p[c], s, q[c]); }
}

// ---------------- pass3: re-run chunk from entry state, emit y. grid = 2048.
__global__ __launch_bounds__(256, 4) void scan_pass3(
    const float* __restrict__ x,
    const float* __restrict__ alpha_log,
    const float* __restrict__ delta,
    const float* __restrict__ bet, const float* __restrict__ gam,
    const float* __restrict__ dtp, const float* __restrict__ dtxp,
    const float* __restrict__ PS,
    float* __restrict__ out)
{
    __shared__ float dts[LC][G];
    __shared__ float dxs[LC][G];
    __shared__ float part[TR * G][NST];   // 16 KB
    const int n    = threadIdx.x;
    const int c    = blockIdx.x & 15;
    const int dblk = (blockIdx.x >> 4) & 63;
    const int b    = blockIdx.x >> 10;
    const int d0   = dblk * G;
    const int rbase = b * LSEQ + c * LC;

    {
        int t = (n & 127) >> 2, g = n & 3;
        if (n < 128) dts[t][g] = dtp [(rbase + t) * DIM + d0 + g];
        else         dxs[t][g] = dtxp[(rbase + t) * DIM + d0 + g];
    }
    float aln[G], s[G];
    #pragma unroll
    for (int g = 0; g < G; ++g) {
        aln[g] = -__expf(alpha_log[(d0 + g) * NST + n]) * LOG2E;
        s[g] = PS[((size_t)(b * DIM + d0 + g) * C + c) * NST + n];
    }
    float4 dl4 = *(const float4*)&delta[d0];
    __syncthreads();

    constexpr int NW = LC / TR;   // 8
    float be[2][TR], ga[2][TR];
    #pragma unroll
    for (int t = 0; t < TR; ++t) {
        be[0][t] = bet[(rbase + t) * NST + n];
        ga[0][t] = gam[(rbase + t) * NST + n];
    }

    #pragma unroll
    for (int w = 0; w < NW; ++w) {
        const int cur = w & 1, nxt = cur ^ 1;
        if (w + 1 < NW) {
            #pragma unroll
            for (int t = 0; t < TR; ++t) {
                be[nxt][t] = bet[(rbase + (w + 1) * TR + t) * NST + n];
                ga[nxt][t] = gam[(rbase + (w + 1) * TR + t) * NST + n];
            }
        }
        #pragma unroll
        for (int t = 0; t < TR; ++t) {
            float4 dt4 = *(const float4*)&dts[w * TR + t][0];
            float4 dx4 = *(const float4*)&dxs[w * TR + t][0];
            const float dta[4] = {dt4.x, dt4.y, dt4.z, dt4.w};
            const float dxa[4] = {dx4.x, dx4.y, dx4.z, dx4.w};
            #pragma unroll
            for (int g = 0; g < G; ++g) {
                float a = fexp2(dta[g] * aln[g]);
                s[g] = fmaf(a, s[g], dxa[g] * be[cur][t]);
                part[t * G + g][n] = s[g] * ga[cur][t];   // 2-way alias: free
            }
        }
        __syncthreads();
        {
            // 16 rows x 256 cols -> 16 row-sums. thread = (row = n>>4, seg m = n&15)
            const int row = n >> 4, m = n & 15, rw = row & 3;
            float sum = 0.f;
            #pragma unroll
            for (int k = 0; k < 16; ++k) {
                int col = m * 16 + ((k + m + 5 * rw) & 15);  // 2-way banks, bijective in k
                sum += part[row][col];
            }
            sum += __shfl_xor(sum, 1);
            sum += __shfl_xor(sum, 2);
            sum += __shfl_xor(sum, 4);
            sum += __shfl_xor(sum, 8);
            if (m == 0) {
                const int tt = row >> 2, g = row & 3;
                const int r = rbase + w * TR + tt;
                const int oidx = r * DIM + d0 + g;
                float dv = (g == 0) ? dl4.x : ((g == 1) ? dl4.y : ((g == 2) ? dl4.z : dl4.w));
                out[oidx] = sum + x[oidx] * dv;
            }
        }
        __syncthreads();
    }
}

extern "C" void kernel_launch(void* const* d_in, const int* in_sizes, int n_in,
                              void* d_out, int out_size, void* d_ws, size_t ws_size,
                              hipStream_t stream) {
    const float* x         = (const float*)d_in[0];
    const float* W_in      = (const float*)d_in[1];
    const float* W_dt      = (const float*)d_in[2];
    const float* b_dt      = (const float*)d_in[3];
    const float* alpha_log = (const float*)d_in[4];
    const float* delta     = (const float*)d_in[5];
    float* out = (float*)d_out;

    // Workspace: PP 9.4MB | bet/gam/dtp/dtxp 4MB | PS/Q 16MB  (~30MB total)
    float* PP   = (float*)d_ws;
    float* bet  = PP   + (size_t)KSPLIT * NROWS * PCOLS;
    float* gam  = bet  + NROWS * NST;
    float* dtp  = gam  + NROWS * NST;
    float* dtxp = dtp  + NROWS * DIM;
    float* PS   = dtxp + NROWS * DIM;
    float* Q    = PS   + (size_t)BAT * DIM * C * NST;

    projA_kernel<<<(NROWS / AROWS) * KSPLIT, 256, 0, stream>>>(x, W_in, PP);
    projB_kernel<<<NROWS / BROWS, 256, 0, stream>>>(x, PP, W_dt, b_dt, bet, gam, dtp, dtxp);
    scan_pass1<<<BAT * (DIM / G) * C, 256, 0, stream>>>(alpha_log, bet, dtp, dtxp, PS, Q);
    scan_pass2<<<BAT * DIM, 256, 0, stream>>>(PS, Q);
    scan_pass3<<<BAT * (DIM / G) * C, 256, 0, stream>>>(x, alpha_log, delta, bet, gam, dtp, dtxp, PS, out);
}